// Round 5
// baseline (116.028 us; speedup 1.0000x reference)
//
#include <hip/hip_runtime.h>
#include <stdint.h>

#define LSEQ 256
#define EMB  256
#define K3F  768
#define SCOFF (4 * 256 * 256 * 6)

typedef short bf16x8 __attribute__((ext_vector_type(8)));
typedef float f32x4  __attribute__((ext_vector_type(4)));

__device__ __forceinline__ uint16_t f2bf(float x) {
    union { float f; uint32_t u; } c; c.f = x;
    uint32_t r = c.u + 0x7fffu + ((c.u >> 16) & 1u);
    return (uint16_t)(r >> 16);
}

// ---------- fused conv: gather (ids/table) + weight bf16-transpose + MFMA GEMM
// grid 768 = 4b * 3g * 8c0 * 8l0; 32c x 32l tile per block, i-chunk 64.
// epilogue: VB[b][l][c]=bf16(acc) and U[b][cm][l][c]=bf16(acc*tw_cm[c]), cm=0..6
template <int K, int PAD>
__device__ __forceinline__ void conv2_body(const float* __restrict__ w,
                                           const float* __restrict__ bias,
                                           const int* __restrict__ ids,
                                           const float* __restrict__ table,
                                           const float* __restrict__ tw,
                                           const float* __restrict__ sw,
                                           uint16_t* __restrict__ VB,
                                           uint16_t* __restrict__ U,
                                           int b, int c0, int l0, int gbase,
                                           uint16_t (*As)[32][72], uint16_t (*Bs)[72],
                                           float (*twb)[32]) {
    const int tid = threadIdx.x;
    {   // stage tw rows (7) + bias into twb[8][32]
        int cm = tid >> 5, cc = tid & 31;
        int gch = gbase + c0 + cc;
        float v;
        if (cm < 6) v = tw[cm * K3F + gch];
        else if (cm == 6) v = sw[gch];
        else v = bias[c0 + cc];
        twb[cm][cc] = v;
    }
    const int lane = tid & 63, wave = tid >> 6;
    const int ms = wave >> 1, ns = wave & 1;
    const int m = lane & 15, q = lane >> 4;
    const int ar = tid >> 3, pb = (tid & 7) * 8;   // row 0..31, 8-elem segment

    // hoist gather ids: row ar covers seq l = l0 - 1 + ar; extra rows 32..35 via tid<32
    const int l1 = l0 - 1 + ar;
    const bool v1 = (l1 >= 0) && (l1 < LSEQ);
    const float* trow1 = v1 ? table + (size_t)ids[(b << 8) + (v1 ? l1 : 0)] * EMB : nullptr;
    const int r2 = 32 + (tid >> 3);                // only meaningful for tid<32
    const int l2 = l0 - 1 + r2;
    const bool v2 = (tid < 32) && (l2 < LSEQ);
    const float* trow2 = v2 ? table + (size_t)ids[(b << 8) + (v2 ? l2 : 0)] * EMB : nullptr;

    f32x4 acc;
#pragma unroll
    for (int z = 0; z < 4; ++z) acc[z] = 0.f;

    for (int i0 = 0; i0 < EMB; i0 += 64) {
        __syncthreads();
        // ---- A: weights w[c0+ar][i0+pb..+7][t] fp32 -> bf16, per t
#pragma unroll
        for (int t = 0; t < K; ++t) {
            const float* wsrc = w + (size_t)(c0 + ar) * (EMB * K) + (size_t)(i0 + pb) * K + t;
            union { uint16_t h[8]; uint32_t d[4]; } pk;
#pragma unroll
            for (int j = 0; j < 8; ++j) pk.h[j] = f2bf(wsrc[j * K]);
            *(uint2*)&As[t][ar][pb]     = make_uint2(pk.d[0], pk.d[1]);
            *(uint2*)&As[t][ar][pb + 4] = make_uint2(pk.d[2], pk.d[3]);
        }
        // ---- B: table rows -> bf16 (rows 0..31 by all, 32..35 by tid<32)
        {
            union { uint16_t h[8]; uint32_t d[4]; } pk;
            if (v1) {
                float4 a = *(const float4*)(trow1 + i0 + pb);
                float4 c = *(const float4*)(trow1 + i0 + pb + 4);
                pk.h[0] = f2bf(a.x); pk.h[1] = f2bf(a.y); pk.h[2] = f2bf(a.z); pk.h[3] = f2bf(a.w);
                pk.h[4] = f2bf(c.x); pk.h[5] = f2bf(c.y); pk.h[6] = f2bf(c.z); pk.h[7] = f2bf(c.w);
            } else {
#pragma unroll
                for (int j = 0; j < 4; ++j) pk.d[j] = 0u;
            }
            *(uint2*)&Bs[ar][pb]     = make_uint2(pk.d[0], pk.d[1]);
            *(uint2*)&Bs[ar][pb + 4] = make_uint2(pk.d[2], pk.d[3]);
        }
        if (tid < 32) {
            union { uint16_t h[8]; uint32_t d[4]; } pk;
            if (v2) {
                float4 a = *(const float4*)(trow2 + i0 + pb);
                float4 c = *(const float4*)(trow2 + i0 + pb + 4);
                pk.h[0] = f2bf(a.x); pk.h[1] = f2bf(a.y); pk.h[2] = f2bf(a.z); pk.h[3] = f2bf(a.w);
                pk.h[4] = f2bf(c.x); pk.h[5] = f2bf(c.y); pk.h[6] = f2bf(c.z); pk.h[7] = f2bf(c.w);
            } else {
#pragma unroll
                for (int j = 0; j < 4; ++j) pk.d[j] = 0u;
            }
            *(uint2*)&Bs[r2][pb]     = make_uint2(pk.d[0], pk.d[1]);
            *(uint2*)&Bs[r2][pb + 4] = make_uint2(pk.d[2], pk.d[3]);
        }
        __syncthreads();
#pragma unroll
        for (int t = 0; t < K; ++t) {
#pragma unroll
            for (int kh = 0; kh < 64; kh += 32) {
                bf16x8 afr = *(const bf16x8*)&As[t][ms * 16 + m][kh + q * 8];
                bf16x8 bfr = *(const bf16x8*)&Bs[ns * 16 + m + t - PAD + 1][kh + q * 8];
                acc = __builtin_amdgcn_mfma_f32_16x16x32_bf16(afr, bfr, acc, 0, 0, 0);
            }
        }
    }
    __syncthreads();
    float (*Cs)[36] = (float(*)[36])As;   // 4,608 B reuse of As
#pragma unroll
    for (int rg = 0; rg < 4; ++rg)
        Cs[ms * 16 + q * 4 + rg][ns * 16 + m] = acc[rg];
    __syncthreads();
    const int l = tid >> 3, cs = (tid & 7) * 4;
    float vals[4];
#pragma unroll
    for (int v = 0; v < 4; ++v) vals[v] = Cs[cs + v][l] + twb[7][cs + v];
    union { uint16_t h[4]; uint32_t d[2]; } pk;
#pragma unroll
    for (int v = 0; v < 4; ++v) pk.h[v] = f2bf(vals[v]);
    uint16_t* vdst = VB + (size_t)(b * 256 + l0 + l) * K3F + gbase + c0 + cs;
    *(uint2*)vdst = *(const uint2*)pk.d;
#pragma unroll
    for (int cm = 0; cm < 7; ++cm) {
#pragma unroll
        for (int v = 0; v < 4; ++v) pk.h[v] = f2bf(vals[v] * twb[cm][cs + v]);
        uint16_t* udst = U + (size_t)((b * 7 + cm) * 256 + l0 + l) * K3F + gbase + c0 + cs;
        *(uint2*)udst = *(const uint2*)pk.d;
    }
}

__global__ __launch_bounds__(256, 2) void k_conv2(const float* __restrict__ w2,
                                                  const float* __restrict__ b2,
                                                  const float* __restrict__ w3,
                                                  const float* __restrict__ b3,
                                                  const float* __restrict__ w4,
                                                  const float* __restrict__ b4,
                                                  const int* __restrict__ ids,
                                                  const float* __restrict__ table,
                                                  const float* __restrict__ tw,
                                                  const float* __restrict__ sw,
                                                  uint16_t* __restrict__ VB,
                                                  uint16_t* __restrict__ U) {
    __shared__ uint16_t As[4][32][72];
    __shared__ uint16_t Bs[36][72];
    __shared__ float twb[8][32];
    int blk = blockIdx.x;                 // 768 = 4b * 3g * 8c0 * 8l0
    int b = blk & 3, rest = blk >> 2;
    int g = rest >> 6, rr = rest & 63;
    int c0 = (rr >> 3) * 32, l0 = (rr & 7) * 32;
    if (g == 0)      conv2_body<2, 0>(w2, b2, ids, table, tw, sw, VB, U, b, c0, l0, 0,   As, Bs, twb);
    else if (g == 1) conv2_body<3, 1>(w3, b3, ids, table, tw, sw, VB, U, b, c0, l0, 256, As, Bs, twb);
    else             conv2_body<4, 1>(w4, b4, ids, table, tw, sw, VB, U, b, c0, l0, 512, As, Bs, twb);
}

// ---------- pair GEMM, one (b,c,i-tile,j-tile) per block: 1792 blocks
__global__ __launch_bounds__(256, 4) void k_pairc(const uint16_t* __restrict__ U,
                                                  const uint16_t* __restrict__ VB,
                                                  const float* __restrict__ tb,
                                                  const float* __restrict__ sb,
                                                  float* __restrict__ dout) {
    __shared__ uint16_t T[64][136];       // rows 0..31 = U tile, 32..63 = VB tile
    int blk = blockIdx.x;                 // jt in low bits -> XCD spread
    int jt = blk & 7, it = (blk >> 3) & 7;
    int c = (blk >> 6) % 7, b = blk / 448;
    int i0 = it * 32, j0 = jt * 32;
    int tid = threadIdx.x;
    int lane = tid & 63, wave = tid >> 6;
    int ms = wave >> 1, ns = wave & 1;
    int m = lane & 15, q = lane >> 4;
    int rs = tid >> 2, off = (tid & 3) * 32;

    const uint16_t* srcA = U + (size_t)((b * 7 + c) * 256 + i0 + rs) * K3F + off;
    const uint16_t* srcB = VB + (size_t)(b * 256 + j0 + (rs - 32)) * K3F + off;
    const uint16_t* src = (rs < 32) ? srcA : srcB;

    f32x4 acc;
#pragma unroll
    for (int z = 0; z < 4; ++z) acc[z] = 0.f;

    for (int kc = 0; kc < K3F; kc += 128) {
        __syncthreads();
#pragma unroll
        for (int s = 0; s < 4; ++s)
            *(bf16x8*)&T[rs][off + s * 8] = *(const bf16x8*)(src + kc + s * 8);
        __syncthreads();
#pragma unroll
        for (int kh = 0; kh < 4; ++kh) {
            bf16x8 afr = *(const bf16x8*)&T[ms * 16 + m][kh * 32 + q * 8];
            bf16x8 bfr = *(const bf16x8*)&T[32 + ns * 16 + m][kh * 32 + q * 8];
            acc = __builtin_amdgcn_mfma_f32_16x16x32_bf16(afr, bfr, acc, 0, 0, 0);
        }
    }
    float bias = (c < 6) ? tb[c] : sb[0];
#pragma unroll
    for (int rg = 0; rg < 4; ++rg) {
        int i = i0 + ms * 16 + q * 4 + rg;
        int j = j0 + ns * 16 + m;
        float v = acc[rg] + bias;
        if (c < 6) dout[((size_t)(b * 256 + i) * 256 + j) * 6 + c] = v;
        else       dout[SCOFF + (size_t)(b * 256 + i) * 256 + j] = v;
    }
}

extern "C" void kernel_launch(void* const* d_in, const int* in_sizes, int n_in,
                              void* d_out, int out_size, void* d_ws, size_t ws_size,
                              hipStream_t stream) {
    const int*   ids   = (const int*)d_in[0];
    const float* table = (const float*)d_in[1];
    const float* w2 = (const float*)d_in[2];
    const float* b2 = (const float*)d_in[3];
    const float* w3 = (const float*)d_in[4];
    const float* b3 = (const float*)d_in[5];
    const float* w4 = (const float*)d_in[6];
    const float* b4 = (const float*)d_in[7];
    const float* tw = (const float*)d_in[8];
    const float* tb = (const float*)d_in[9];
    const float* sw = (const float*)d_in[10];
    const float* sb = (const float*)d_in[11];
    float* dout = (float*)d_out;

    uint8_t* wsb = (uint8_t*)d_ws;
    uint16_t* VB = (uint16_t*)(wsb + 0);         //  1,572,864 B
    uint16_t* U  = (uint16_t*)(wsb + 1572864);   // 11,010,048 B

    hipLaunchKernelGGL(k_conv2, dim3(768), dim3(256), 0, stream,
                       w2, b2, w3, b3, w4, b4, ids, table, tw, sw, VB, U);
    hipLaunchKernelGGL(k_pairc, dim3(1792), dim3(256), 0, stream, U, VB, tb, sb, dout);
}

// Round 6
// 109.249 us; speedup vs baseline: 1.0621x; 1.0621x over previous
//
#include <hip/hip_runtime.h>
#include <stdint.h>

#define LSEQ 256
#define EMB  256
#define K3F  768
#define SCOFF (4 * 256 * 256 * 6)

typedef short bf16x8 __attribute__((ext_vector_type(8)));
typedef float f32x4  __attribute__((ext_vector_type(4)));

__device__ __forceinline__ uint16_t f2bf(float x) {
    union { float f; uint32_t u; } c; c.f = x;
    uint32_t r = c.u + 0x7fffu + ((c.u >> 16) & 1u);
    return (uint16_t)(r >> 16);
}

// ---------- prep: gather->embB bf16 (rows 4+l, zero halo), wprep->Wt[t][c][i] bf16
// grid 804 = 32 gather + 4 pad + 768 wprep (one thread per (c,i), K loads/stores)
__global__ __launch_bounds__(256) void k_prep(const int* __restrict__ ids,
                                              const float* __restrict__ table,
                                              const float* __restrict__ w2,
                                              const float* __restrict__ w3,
                                              const float* __restrict__ w4,
                                              uint16_t* __restrict__ embB,
                                              uint16_t* __restrict__ Wt2,
                                              uint16_t* __restrict__ Wt3,
                                              uint16_t* __restrict__ Wt4) {
    int blk = blockIdx.x, tid = threadIdx.x;
    if (blk < 32) {                       // gather: 4b x 8 l-chunks of 32
        int b = blk >> 3, l0 = (blk & 7) << 5;
        int r = tid >> 3, p = tid & 7;
        int id = ids[(b << 8) + l0 + r];
        const float* src = table + (size_t)id * EMB + p * 32;
        uint16_t* dst = embB + (size_t)(b * 272 + 4 + l0 + r) * 256 + p * 32;
#pragma unroll
        for (int s = 0; s < 8; ++s) {
            float4 v = *(const float4*)(src + 4 * s);
            uint32_t lo = f2bf(v.x) | ((uint32_t)f2bf(v.y) << 16);
            uint32_t hi = f2bf(v.z) | ((uint32_t)f2bf(v.w) << 16);
            *(uint2*)(dst + 4 * s) = make_uint2(lo, hi);
        }
    } else if (blk < 36) {                // zero pad rows 0..3, 260..271
        int b = blk - 32;
        int ri = tid >> 4;
        int row = ri < 4 ? ri : 256 + ri;
        int off = (tid & 15) * 16;
        uint16_t* dst = embB + (size_t)(b * 272 + row) * 256 + off;
        *(uint4*)dst = make_uint4(0, 0, 0, 0);
        *(uint4*)(dst + 8) = make_uint4(0, 0, 0, 0);
    } else {                              // wprep: thread = (c,i), 65536 per group
        int n = (blk - 36) * 256 + tid;
        if (n < 65536) {
            int c = n >> 8, i = n & 255;
            float2 v = *(const float2*)(w2 + (c << 9) + (i << 1));
            Wt2[c * 256 + i]         = f2bf(v.x);
            Wt2[65536 + c * 256 + i] = f2bf(v.y);
        } else if (n < 131072) {
            int m = n - 65536;
            int c = m >> 8, i = m & 255;
            const float* s = w3 + c * 768 + i * 3;
#pragma unroll
            for (int t = 0; t < 3; ++t)
                Wt3[t * 65536 + c * 256 + i] = f2bf(s[t]);
        } else {
            int m = n - 131072;
            int c = m >> 8, i = m & 255;
            float4 v = *(const float4*)(w4 + (c << 10) + (i << 2));
            Wt4[c * 256 + i]              = f2bf(v.x);
            Wt4[65536 + c * 256 + i]      = f2bf(v.y);
            Wt4[2 * 65536 + c * 256 + i]  = f2bf(v.z);
            Wt4[3 * 65536 + c * 256 + i]  = f2bf(v.w);
        }
    }
}

// ---------- conv as MFMA GEMM, 32c x 32l tiles, i-chunk 64 (R4 proven form)
template <int K, int PAD>
__device__ __forceinline__ void convg_body(const uint16_t* __restrict__ Wt,
                                           const float* __restrict__ bias,
                                           const uint16_t* __restrict__ embB,
                                           const float* __restrict__ tw,
                                           const float* __restrict__ sw,
                                           uint16_t* __restrict__ VB,
                                           uint16_t* __restrict__ U,
                                           int b, int c0, int l0, int gbase,
                                           uint16_t (*As)[32][72], uint16_t (*Bs)[72],
                                           float (*twb)[32]) {
    const int tid = threadIdx.x;
    {   // stage tw rows (7) + bias into twb[8][32]
        int cm = tid >> 5, cc = tid & 31;
        int gch = gbase + c0 + cc;
        float v;
        if (cm < 6) v = tw[cm * K3F + gch];
        else if (cm == 6) v = sw[gch];
        else v = bias[c0 + cc];
        twb[cm][cc] = v;
    }
    const int lane = tid & 63, wave = tid >> 6;
    const int ms = wave >> 1, ns = wave & 1;
    const int m = lane & 15, q = lane >> 4;
    const int ar = tid >> 3, aseg = (tid & 7) * 8;

    f32x4 acc;
#pragma unroll
    for (int z = 0; z < 4; ++z) acc[z] = 0.f;

    for (int i0 = 0; i0 < EMB; i0 += 64) {
        __syncthreads();
#pragma unroll
        for (int t = 0; t < K; ++t) {
            const uint16_t* src = Wt + (size_t)((t * 256 + c0 + ar) * 256 + i0) + aseg;
            *(bf16x8*)&As[t][ar][aseg] = *(const bf16x8*)src;
        }
        {   // B rows: embB rows 3+l0 .. 3+l0+35 (36 rows x 64 i)
            const uint16_t* src = embB + (size_t)(b * 272 + 3 + l0 + ar) * 256 + i0 + aseg;
            *(bf16x8*)&Bs[ar][aseg] = *(const bf16x8*)src;
            if (tid < 32) {
                int r2 = 32 + (tid >> 3);
                const uint16_t* s2 = embB + (size_t)(b * 272 + 3 + l0 + r2) * 256 + i0 + aseg;
                *(bf16x8*)&Bs[r2][aseg] = *(const bf16x8*)s2;
            }
        }
        __syncthreads();
#pragma unroll
        for (int t = 0; t < K; ++t) {
#pragma unroll
            for (int kh = 0; kh < 64; kh += 32) {
                bf16x8 afr = *(const bf16x8*)&As[t][ms * 16 + m][kh + q * 8];
                bf16x8 bfr = *(const bf16x8*)&Bs[ns * 16 + m + t - PAD + 1][kh + q * 8];
                acc = __builtin_amdgcn_mfma_f32_16x16x32_bf16(afr, bfr, acc, 0, 0, 0);
            }
        }
    }
    __syncthreads();
    float (*Cs)[36] = (float(*)[36])As;   // 4,608 B reuse
#pragma unroll
    for (int rg = 0; rg < 4; ++rg)
        Cs[ms * 16 + q * 4 + rg][ns * 16 + m] = acc[rg];
    __syncthreads();
    const int l = tid >> 3, cs = (tid & 7) * 4;
    float vals[4];
#pragma unroll
    for (int v = 0; v < 4; ++v) vals[v] = Cs[cs + v][l] + twb[7][cs + v];
    union { uint16_t h[4]; uint32_t d[2]; } pk;
#pragma unroll
    for (int v = 0; v < 4; ++v) pk.h[v] = f2bf(vals[v]);
    uint16_t* vdst = VB + (size_t)(b * 256 + l0 + l) * K3F + gbase + c0 + cs;
    *(uint2*)vdst = *(const uint2*)pk.d;
#pragma unroll
    for (int cm = 0; cm < 7; ++cm) {
#pragma unroll
        for (int v = 0; v < 4; ++v) pk.h[v] = f2bf(vals[v] * twb[cm][cs + v]);
        uint16_t* udst = U + (size_t)((b * 7 + cm) * 256 + l0 + l) * K3F + gbase + c0 + cs;
        *(uint2*)udst = *(const uint2*)pk.d;
    }
}

__global__ __launch_bounds__(256, 2) void k_convg(const uint16_t* __restrict__ Wt2,
                                                  const uint16_t* __restrict__ Wt3,
                                                  const uint16_t* __restrict__ Wt4,
                                                  const float* __restrict__ b2,
                                                  const float* __restrict__ b3,
                                                  const float* __restrict__ b4,
                                                  const uint16_t* __restrict__ embB,
                                                  const float* __restrict__ tw,
                                                  const float* __restrict__ sw,
                                                  uint16_t* __restrict__ VB,
                                                  uint16_t* __restrict__ U) {
    __shared__ uint16_t As[4][32][72];
    __shared__ uint16_t Bs[36][72];
    __shared__ float twb[8][32];
    int blk = blockIdx.x;                 // 768 = 4b * 3g * 8c0 * 8l0
    int b = blk & 3, rest = blk >> 2;
    int g = rest >> 6, rr = rest & 63;
    int c0 = (rr >> 3) * 32, l0 = (rr & 7) * 32;
    if (g == 0)      convg_body<2, 0>(Wt2, b2, embB, tw, sw, VB, U, b, c0, l0, 0,   As, Bs, twb);
    else if (g == 1) convg_body<3, 1>(Wt3, b3, embB, tw, sw, VB, U, b, c0, l0, 256, As, Bs, twb);
    else             convg_body<4, 1>(Wt4, b4, embB, tw, sw, VB, U, b, c0, l0, 512, As, Bs, twb);
}

// ---------- pair GEMM: block = (b, c, i-tile 32, j-pair 64): 896 blocks
// same-(b,c,it) blocks are 224 apart (224 % 8 == 0 -> same XCD, U rows L2-hot)
__global__ __launch_bounds__(256, 4) void k_pairc2(const uint16_t* __restrict__ U,
                                                   const uint16_t* __restrict__ VB,
                                                   const float* __restrict__ tb,
                                                   const float* __restrict__ sb,
                                                   float* __restrict__ dout) {
    __shared__ uint16_t T[96][136];       // rows 0..31 = U(i), 32..95 = VB(j0..j0+63)
    int blk = blockIdx.x;
    int b = blk & 3, it = (blk >> 2) & 7;
    int rest = blk >> 5;
    int c = rest % 7, jp = rest / 7;
    int i0 = it * 32, j0 = jp * 64;
    int tid = threadIdx.x;
    int lane = tid & 63, wave = tid >> 6;
    int iw = wave >> 1, jw = wave & 1;
    int m = lane & 15, q = lane >> 4;
    int rr = tid >> 3, seg = (tid & 7) * 16;   // 32 rows/pass, 8 thr/row, 16 halfs

    const uint16_t* srcp[3];
    srcp[0] = U + (size_t)((b * 7 + c) * 256 + i0 + rr) * K3F + seg;
    srcp[1] = VB + (size_t)(b * 256 + j0 + rr) * K3F + seg;
    srcp[2] = VB + (size_t)(b * 256 + j0 + 32 + rr) * K3F + seg;

    f32x4 acc[2];
#pragma unroll
    for (int n = 0; n < 2; ++n)
#pragma unroll
        for (int z = 0; z < 4; ++z) acc[n][z] = 0.f;

    for (int kc = 0; kc < K3F; kc += 128) {
        __syncthreads();
#pragma unroll
        for (int p = 0; p < 3; ++p) {
            const uint16_t* s = srcp[p] + kc;
            *(bf16x8*)&T[p * 32 + rr][seg]     = *(const bf16x8*)s;
            *(bf16x8*)&T[p * 32 + rr][seg + 8] = *(const bf16x8*)(s + 8);
        }
        __syncthreads();
#pragma unroll
        for (int kh = 0; kh < 4; ++kh) {
            bf16x8 afr  = *(const bf16x8*)&T[iw * 16 + m][kh * 32 + q * 8];
            bf16x8 bfr0 = *(const bf16x8*)&T[32 + jw * 32 + m][kh * 32 + q * 8];
            bf16x8 bfr1 = *(const bf16x8*)&T[32 + jw * 32 + 16 + m][kh * 32 + q * 8];
            acc[0] = __builtin_amdgcn_mfma_f32_16x16x32_bf16(afr, bfr0, acc[0], 0, 0, 0);
            acc[1] = __builtin_amdgcn_mfma_f32_16x16x32_bf16(afr, bfr1, acc[1], 0, 0, 0);
        }
    }
    float bias = (c < 6) ? tb[c] : sb[0];
#pragma unroll
    for (int n = 0; n < 2; ++n)
#pragma unroll
        for (int rg = 0; rg < 4; ++rg) {
            int i = i0 + iw * 16 + q * 4 + rg;
            int j = j0 + jw * 32 + n * 16 + m;
            float v = acc[n][rg] + bias;
            if (c < 6) dout[((size_t)(b * 256 + i) * 256 + j) * 6 + c] = v;
            else       dout[SCOFF + (size_t)(b * 256 + i) * 256 + j] = v;
        }
}

extern "C" void kernel_launch(void* const* d_in, const int* in_sizes, int n_in,
                              void* d_out, int out_size, void* d_ws, size_t ws_size,
                              hipStream_t stream) {
    const int*   ids   = (const int*)d_in[0];
    const float* table = (const float*)d_in[1];
    const float* w2 = (const float*)d_in[2];
    const float* b2 = (const float*)d_in[3];
    const float* w3 = (const float*)d_in[4];
    const float* b3 = (const float*)d_in[5];
    const float* w4 = (const float*)d_in[6];
    const float* b4 = (const float*)d_in[7];
    const float* tw = (const float*)d_in[8];
    const float* tb = (const float*)d_in[9];
    const float* sw = (const float*)d_in[10];
    const float* sb = (const float*)d_in[11];
    float* dout = (float*)d_out;

    uint8_t* wsb = (uint8_t*)d_ws;
    uint16_t* VB   = (uint16_t*)(wsb + 0);           //  1,572,864 B
    uint16_t* U    = (uint16_t*)(wsb + 1572864);     // 11,010,048 B
    uint16_t* embB = (uint16_t*)(wsb + 12582912);    //    557,056 B
    uint16_t* Wt2  = (uint16_t*)(wsb + 13139968);    //    262,144 B
    uint16_t* Wt3  = (uint16_t*)(wsb + 13402112);    //    393,216 B
    uint16_t* Wt4  = (uint16_t*)(wsb + 13795328);    //    524,288 B -> 14,319,616 total

    hipLaunchKernelGGL(k_prep,   dim3(804), dim3(256), 0, stream,
                       ids, table, w2, w3, w4, embB, Wt2, Wt3, Wt4);
    hipLaunchKernelGGL(k_convg,  dim3(768), dim3(256), 0, stream,
                       Wt2, Wt3, Wt4, b2, b3, b4, embB, tw, sw, VB, U);
    hipLaunchKernelGGL(k_pairc2, dim3(896), dim3(256), 0, stream, U, VB, tb, sb, dout);
}